// Round 1
// baseline (476.773 us; speedup 1.0000x reference)
//
#include <hip/hip_runtime.h>

#define NN 50000
#define EE 800000

typedef __attribute__((ext_vector_type(4))) float f32x4;
typedef __attribute__((ext_vector_type(8))) short bf16x8;

__device__ inline unsigned short f2b(float f) {
    unsigned u = __float_as_uint(f);
    u += 0x7fff + ((u >> 16) & 1);   // RNE
    return (unsigned short)(u >> 16);
}
__device__ inline float b2f(unsigned short b) {
    return __uint_as_float(((unsigned)b) << 16);
}

// ---- convert 4 weight matrices f32 -> bf16 bits into ws ----
__global__ void convert_w(const float* __restrict__ Wq, const float* __restrict__ Wk,
                          const float* __restrict__ Wv, const float* __restrict__ Wo,
                          unsigned short* __restrict__ out) {
    int g = blockIdx.x * 256 + threadIdx.x;     // 65536 threads
    int which = g >> 14, idx = g & 16383;
    const float* s = (which == 0) ? Wq : (which == 1) ? Wk : (which == 2) ? Wv : Wo;
    out[g] = f2b(s[idx]);
}

// ---- GEMM: C[M,128] (bf16) = A[M,128] (f32) @ W^T (bf16) + bias ----
__global__ __launch_bounds__(256) void gemm_proj(
    const float* __restrict__ A, int M,
    const unsigned short* __restrict__ W,
    const float* __restrict__ bias,
    unsigned short* __restrict__ C)
{
    __shared__ __align__(16) unsigned short As[128 * 128];
    __shared__ __align__(16) unsigned short Ws[128 * 128];
    const int t = threadIdx.x;
    const long mbase = (long)blockIdx.x * 128;

#pragma unroll
    for (int i = 0; i < 8; ++i) {               // stage W (swizzled)
        int chunk = t + i * 256;
        int row = chunk >> 4, kc = chunk & 15;
        uint4 w = *(const uint4*)(W + (row << 7) + (kc << 3));
        *(uint4*)(Ws + (row << 7) + (((kc ^ (row & 15))) << 3)) = w;
    }
#pragma unroll
    for (int i = 0; i < 8; ++i) {               // stage A with f32->bf16 convert
        int chunk = t + i * 256;
        int row = chunk >> 4, kc = chunk & 15;
        long m = mbase + row;
        unsigned short tmp[8];
        if (m < M) {
            const float* ap = A + m * 128 + (kc << 3);
#pragma unroll
            for (int j = 0; j < 8; ++j) tmp[j] = f2b(ap[j]);
        } else {
#pragma unroll
            for (int j = 0; j < 8; ++j) tmp[j] = 0;
        }
        *(uint4*)(As + (row << 7) + (((kc ^ (row & 15))) << 3)) = *(uint4*)tmp;
    }
    __syncthreads();

    const int wave = t >> 6, lane = t & 63;
    const int lr = lane & 15, lk = lane >> 4;
    f32x4 acc[2][8];
#pragma unroll
    for (int i = 0; i < 2; ++i)
#pragma unroll
        for (int j = 0; j < 8; ++j) acc[i][j] = (f32x4){0.f, 0.f, 0.f, 0.f};

#pragma unroll
    for (int s = 0; s < 4; ++s) {
        bf16x8 a[2];
#pragma unroll
        for (int i = 0; i < 2; ++i) {
            int row = wave * 32 + i * 16 + lr;
            int kc = s * 4 + lk;
            a[i] = *(const bf16x8*)(As + (row << 7) + (((kc ^ (row & 15))) << 3));
        }
#pragma unroll
        for (int j = 0; j < 8; ++j) {
            int row = j * 16 + lr;              // W row == output col
            int kc = s * 4 + lk;
            bf16x8 b = *(const bf16x8*)(Ws + (row << 7) + (((kc ^ (row & 15))) << 3));
            acc[0][j] = __builtin_amdgcn_mfma_f32_16x16x32_bf16(a[0], b, acc[0][j], 0, 0, 0);
            acc[1][j] = __builtin_amdgcn_mfma_f32_16x16x32_bf16(a[1], b, acc[1][j], 0, 0, 0);
        }
    }
#pragma unroll
    for (int i = 0; i < 2; ++i)
#pragma unroll
        for (int j = 0; j < 8; ++j) {
            int col = j * 16 + lr;
            float bv_ = bias[col];
#pragma unroll
            for (int r = 0; r < 4; ++r) {
                long m = mbase + wave * 32 + i * 16 + lk * 4 + r;
                if (m < M) C[m * 128 + col] = f2b(acc[i][j][r] + bv_);
            }
        }
}

// ---- output GEMM: out[N,128] f32 = mish( (Vb ⊙ SS) @ Wo^T + bo ) ----
__global__ __launch_bounds__(256) void gemm_out_k(
    const unsigned short* __restrict__ Vb,
    const float* __restrict__ SS,
    const unsigned short* __restrict__ W,
    const float* __restrict__ bias,
    float* __restrict__ Out)
{
    __shared__ __align__(16) unsigned short As[128 * 128];
    __shared__ __align__(16) unsigned short Ws[128 * 128];
    const int t = threadIdx.x;
    const long mbase = (long)blockIdx.x * 128;

#pragma unroll
    for (int i = 0; i < 8; ++i) {
        int chunk = t + i * 256;
        int row = chunk >> 4, kc = chunk & 15;
        uint4 w = *(const uint4*)(W + (row << 7) + (kc << 3));
        *(uint4*)(Ws + (row << 7) + (((kc ^ (row & 15))) << 3)) = w;
    }
#pragma unroll
    for (int i = 0; i < 8; ++i) {
        int chunk = t + i * 256;
        int row = chunk >> 4, kc = chunk & 15;
        long m = mbase + row;
        unsigned short tmp[8];
        if (m < NN) {
            float ss = SS[m * 8 + (kc >> 1)];
            uint4 u = *(const uint4*)(Vb + m * 128 + (kc << 3));
            unsigned arr[4] = {u.x, u.y, u.z, u.w};
#pragma unroll
            for (int jj = 0; jj < 4; ++jj) {
                float lo = __uint_as_float(arr[jj] << 16) * ss;
                float hi = __uint_as_float(arr[jj] & 0xffff0000u) * ss;
                tmp[2 * jj] = f2b(lo);
                tmp[2 * jj + 1] = f2b(hi);
            }
        } else {
#pragma unroll
            for (int j = 0; j < 8; ++j) tmp[j] = 0;
        }
        *(uint4*)(As + (row << 7) + (((kc ^ (row & 15))) << 3)) = *(uint4*)tmp;
    }
    __syncthreads();

    const int wave = t >> 6, lane = t & 63;
    const int lr = lane & 15, lk = lane >> 4;
    f32x4 acc[2][8];
#pragma unroll
    for (int i = 0; i < 2; ++i)
#pragma unroll
        for (int j = 0; j < 8; ++j) acc[i][j] = (f32x4){0.f, 0.f, 0.f, 0.f};

#pragma unroll
    for (int s = 0; s < 4; ++s) {
        bf16x8 a[2];
#pragma unroll
        for (int i = 0; i < 2; ++i) {
            int row = wave * 32 + i * 16 + lr;
            int kc = s * 4 + lk;
            a[i] = *(const bf16x8*)(As + (row << 7) + (((kc ^ (row & 15))) << 3));
        }
#pragma unroll
        for (int j = 0; j < 8; ++j) {
            int row = j * 16 + lr;
            int kc = s * 4 + lk;
            bf16x8 b = *(const bf16x8*)(Ws + (row << 7) + (((kc ^ (row & 15))) << 3));
            acc[0][j] = __builtin_amdgcn_mfma_f32_16x16x32_bf16(a[0], b, acc[0][j], 0, 0, 0);
            acc[1][j] = __builtin_amdgcn_mfma_f32_16x16x32_bf16(a[1], b, acc[1][j], 0, 0, 0);
        }
    }
#pragma unroll
    for (int i = 0; i < 2; ++i)
#pragma unroll
        for (int j = 0; j < 8; ++j) {
            int col = j * 16 + lr;
            float bv_ = bias[col];
#pragma unroll
            for (int r = 0; r < 4; ++r) {
                long m = mbase + wave * 32 + i * 16 + lk * 4 + r;
                if (m < NN) {
                    float x = acc[i][j][r] + bv_;
                    float sp = (x > 15.f) ? x : log1pf(expf(x));
                    Out[m * 128 + col] = x * tanhf(sp);
                }
            }
        }
}

// ---- per (edge,head): logits -> exp -> store + segment sums ----
__global__ void edge_logits_k(
    const unsigned short* __restrict__ Kb,
    const unsigned short* __restrict__ Qb,
    const int* __restrict__ src, const int* __restrict__ dst,
    float* __restrict__ e1, float* __restrict__ e2, float* __restrict__ e3,
    float* __restrict__ S1, float* __restrict__ S2, float* __restrict__ S3)
{
    long g = (long)blockIdx.x * 256 + threadIdx.x;   // E*H threads exactly
    int e = (int)(g >> 3), h = (int)(g & 7);
    int sn = src[e], dn = dst[e];
    const unsigned short* kp = Kb + (long)e * 128 + h * 16;
    const unsigned short* qs = Qb + (long)sn * 128 + h * 16;
    const unsigned short* qd = Qb + (long)dn * 128 + h * 16;

    float kf[16], qsf[16], qdf[16];
    {
        uint4 u0 = *(const uint4*)kp, u1 = *(const uint4*)(kp + 8);
        unsigned a[8] = {u0.x, u0.y, u0.z, u0.w, u1.x, u1.y, u1.z, u1.w};
#pragma unroll
        for (int i = 0; i < 8; ++i) { kf[2*i] = __uint_as_float(a[i] << 16); kf[2*i+1] = __uint_as_float(a[i] & 0xffff0000u); }
    }
    {
        uint4 u0 = *(const uint4*)qs, u1 = *(const uint4*)(qs + 8);
        unsigned a[8] = {u0.x, u0.y, u0.z, u0.w, u1.x, u1.y, u1.z, u1.w};
#pragma unroll
        for (int i = 0; i < 8; ++i) { qsf[2*i] = __uint_as_float(a[i] << 16); qsf[2*i+1] = __uint_as_float(a[i] & 0xffff0000u); }
    }
    {
        uint4 u0 = *(const uint4*)qd, u1 = *(const uint4*)(qd + 8);
        unsigned a[8] = {u0.x, u0.y, u0.z, u0.w, u1.x, u1.y, u1.z, u1.w};
#pragma unroll
        for (int i = 0; i < 8; ++i) { qdf[2*i] = __uint_as_float(a[i] << 16); qdf[2*i+1] = __uint_as_float(a[i] & 0xffff0000u); }
    }

    float din = 0.f, dout = 0.f, ddiag = 0.f;
#pragma unroll
    for (int j = 0; j < 16; ++j) {
        din   += qsf[j] * kf[j];
        dout  += qdf[j] * kf[j];
        ddiag += qsf[j] * qdf[j];
    }
    float v1 = __expf(din * 0.25f);
    float v2 = __expf(dout * 0.25f);
    float v3 = __expf(ddiag * 0.25f);
    e1[g] = v1; e2[g] = v2; e3[g] = v3;
    atomicAdd(&S1[dn * 8 + h], v1);
    atomicAdd(&S2[dn * 8 + h], v2);
    atomicAdd(&S3[dn * 8 + h], v3);
}

// ---- per (edge,head): normalized score * atten -> SS ----
__global__ void score_k(
    const float* __restrict__ e1, const float* __restrict__ e2, const float* __restrict__ e3,
    const float* __restrict__ S1, const float* __restrict__ S2, const float* __restrict__ S3,
    const float* __restrict__ dist, const float* __restrict__ lam,
    const int* __restrict__ dst, float* __restrict__ SSa)
{
    long g = (long)blockIdx.x * 256 + threadIdx.x;
    int e = (int)(g >> 3), h = (int)(g & 7);
    int dn = dst[e];
    float at = powf(dist[e], lam[0]);
    float sc = e1[g] / (S1[dn * 8 + h] + 1e-12f)
             + e2[g] / (S2[dn * 8 + h] + 1e-12f)
             + e3[g] / (S3[dn * 8 + h] + 1e-12f);
    atomicAdd(&SSa[dn * 8 + h], sc * at);
}

extern "C" void kernel_launch(void* const* d_in, const int* in_sizes, int n_in,
                              void* d_out, int out_size, void* d_ws, size_t ws_size,
                              hipStream_t stream)
{
    const float* h_node = (const float*)d_in[0];
    const float* h_edge = (const float*)d_in[1];
    const float* dist   = (const float*)d_in[2];
    const float* Wq = (const float*)d_in[3];
    const float* bq = (const float*)d_in[4];
    const float* Wk = (const float*)d_in[5];
    const float* bk = (const float*)d_in[6];
    const float* Wv = (const float*)d_in[7];
    const float* bv = (const float*)d_in[8];
    const float* Wo = (const float*)d_in[9];
    const float* bo = (const float*)d_in[10];
    const float* lam = (const float*)d_in[11];
    const int* src = (const int*)d_in[12];
    const int* dst = (const int*)d_in[13];
    float* out = (float*)d_out;

    char* ws = (char*)d_ws;
    unsigned short* Wb = (unsigned short*)ws;                 // 4 x [128][128] bf16
    unsigned short* Qb = (unsigned short*)(ws + 131072);
    unsigned short* Vb = Qb + (size_t)NN * 128;
    unsigned short* Kb = Vb + (size_t)NN * 128;
    float* e1  = (float*)(Kb + (size_t)EE * 128);
    float* e2  = e1 + (size_t)EE * 8;
    float* e3  = e2 + (size_t)EE * 8;
    float* S1  = e3 + (size_t)EE * 8;
    float* S2  = S1 + (size_t)NN * 8;
    float* S3  = S2 + (size_t)NN * 8;
    float* SSa = S3 + (size_t)NN * 8;

    // zero S1,S2,S3,SS (contiguous 6.4 MB)
    hipMemsetAsync(S1, 0, (size_t)NN * 8 * 4 * 4, stream);

    convert_w<<<256, 256, 0, stream>>>(Wq, Wk, Wv, Wo, Wb);
    gemm_proj<<<391, 256, 0, stream>>>(h_node, NN, Wb,               bq, Qb);  // q
    gemm_proj<<<391, 256, 0, stream>>>(h_node, NN, Wb + 2 * 16384,   bv, Vb);  // v
    gemm_proj<<<6250, 256, 0, stream>>>(h_edge, EE, Wb + 1 * 16384,  bk, Kb);  // k
    edge_logits_k<<<25000, 256, 0, stream>>>(Kb, Qb, src, dst, e1, e2, e3, S1, S2, S3);
    score_k<<<25000, 256, 0, stream>>>(e1, e2, e3, S1, S2, S3, dist, lam, dst, SSa);
    gemm_out_k<<<391, 256, 0, stream>>>(Vb, SSa, Wb + 3 * 16384, bo, out);
}